// Round 21
// baseline (355.127 us; speedup 1.0000x reference)
//
#include <hip/hip_runtime.h>
#include <hip/hip_bf16.h>
#include <cstddef>

#define IN_DIM 128
#define MEM 256
#define KTOT 384
#define NLEAF 65536
#define NBLK_TAIL 8

typedef float f32x4 __attribute__((ext_vector_type(4)));
typedef short s16x8 __attribute__((ext_vector_type(8)));
typedef unsigned int u32;

__device__ inline unsigned short f2bf(float f){
    unsigned int u = __builtin_bit_cast(unsigned int, f);
    u += 0x7fff + ((u >> 16) & 1);
    return (unsigned short)(u >> 16);
}

__device__ inline void gld_lds16(const void* g, void* l){
    __builtin_amdgcn_global_load_lds((const __attribute__((address_space(1))) u32*)g,
                                     (__attribute__((address_space(3))) u32*)l, 16, 0, 0);
}
// device-coherent (SC0|SC1): read from coherence point, bypass stale L1/L2
__device__ inline void gld_lds16_dev(const void* g, void* l){
    __builtin_amdgcn_global_load_lds((const __attribute__((address_space(1))) u32*)g,
                                     (__attribute__((address_space(3))) u32*)l, 16, 0, 17);
}
// write-through device-coherent stores
__device__ inline void st16_dev(unsigned short* p, unsigned short v){
    unsigned int vv = v;
    asm volatile("global_store_short %0, %1, off sc0 sc1" :: "v"(p), "v"(vv) : "memory");
}
__device__ inline void st32_dev(float* p, float v){
    asm volatile("global_store_dword %0, %1, off sc0 sc1" :: "v"(p), "v"(v) : "memory");
}

__device__ inline float fsigm(float x){
    return __builtin_amdgcn_rcpf(1.f + __expf(-x));
}
__device__ inline float ftanh(float x){
    return 2.f * __builtin_amdgcn_rcpf(1.f + __expf(-2.f * x)) - 1.f;
}

// A-arena element offsets: leaf (l=16) at 0, stride 128; levels 15..0 stride 384.
__host__ __device__ inline size_t offA(int l){
    if (l == 16) return 0;
    return 8388608u + 384u * (65536u - (1u << (l + 1)));
}
#define ARENA_ELEMS 33554048u
#define ARENA_PAD   65536u

// FENCE-FREE grid barrier (8 co-resident blocks).
__device__ inline void grid_barrier_nf(unsigned* ctr, unsigned target){
    asm volatile("s_waitcnt vmcnt(0)" ::: "memory");
    __syncthreads();
    if (threadIdx.x == 0){
        __hip_atomic_fetch_add(ctr, 1u, __ATOMIC_RELAXED, __HIP_MEMORY_SCOPE_AGENT);
        while (__hip_atomic_load(ctr, __ATOMIC_RELAXED, __HIP_MEMORY_SCOPE_AGENT) < target)
            __builtin_amdgcn_s_sleep(2);
    }
    __syncthreads();
}

// ---------------- pack: W (+bias, +ctr reset) and LEAF x rows only
__global__ void pack_kernel(const float* __restrict__ x,
                            const float* __restrict__ W_ih, const float* __restrict__ b_ih,
                            const float* __restrict__ W_hh, const float* __restrict__ b_hh,
                            unsigned short* __restrict__ Wp, float* __restrict__ bp,
                            unsigned short* __restrict__ Aarena, unsigned* __restrict__ ctr){
    const int stride = gridDim.x * blockDim.x;
    const int tid0 = blockIdx.x * blockDim.x + threadIdx.x;
    if (tid0 == 0){ ctr[0] = 0; }

    for (int g = tid0; g < 1024 * 48; g += stride){
        int row = g / 48, ko = (g - row * 48) * 8;
        const float* s = (ko < IN_DIM) ? (W_ih + (size_t)row * IN_DIM + ko)
                                       : (W_hh + (size_t)row * MEM + (ko - IN_DIM));
        f32x4 v0 = *(const f32x4*)s, v1 = *(const f32x4*)(s + 4);
        s16x8 o;
        #pragma unroll
        for (int e = 0; e < 4; ++e){ o[e] = (short)f2bf(v0[e]); o[4+e] = (short)f2bf(v1[e]); }
        *(s16x8*)(Wp + (size_t)row * KTOT + ko) = o;
        if (ko == 0) bp[row] = b_ih[row] + b_hh[row];
    }

    const int TOTAL_G = 65536 * 16;
    for (int g = tid0; g < TOTAL_G; g += stride){
        int j  = g >> 4;
        int ko = (g & 15) * 8;
        const f32x4* s = (const f32x4*)(x + (size_t)(65535 + j) * IN_DIM + ko);
        f32x4 v0 = s[0], v1 = s[1];
        s16x8 o;
        #pragma unroll
        for (int e = 0; e < 4; ++e){ o[e] = (short)f2bf(v0[e]); o[4+e] = (short)f2bf(v1[e]); }
        *(s16x8*)(Aarena + (size_t)j * IN_DIM + ko) = o;
    }
}

// ================= 8-phase-style 256-row GEMM + LSTM + pair-sum (l15, l14) =================
template<int NK, bool PACKX>
__global__ __launch_bounds__(512, 1) void gemm_lstm8p_kernel(
    const unsigned short* __restrict__ A, int n,
    const unsigned short* __restrict__ Wp, const float* __restrict__ bp,
    const float* __restrict__ csum_in,
    unsigned short* __restrict__ A_next, float* __restrict__ csum_out,
    const float* __restrict__ xsrc, unsigned short* __restrict__ arena)
{
    __shared__ __align__(16) unsigned short As[2][2][128 * 64];   // [buf][half] 64 KB
    __shared__ __align__(16) unsigned short Bs[2][2][128 * 64];   // 64 KB

    const int tid  = threadIdx.x;
    const int lane = tid & 63;
    const int wid  = tid >> 6;        // 0..7
    const int wm   = wid >> 2;        // A row-half (128 rows)
    const int wn   = wid & 3;         // mem 16-col group
    const int row0 = blockIdx.x * 256;
    const int m0   = blockIdx.y * 64;
    const int mg   = m0 + wn * 16 + (lane & 15);

    auto stageA = [&](int kt, int h){
        #pragma unroll
        for (int i = 0; i < 2; ++i){
            int p  = i * 512 + tid;
            int r  = p >> 3;
            int ls = (p & 7) ^ (r & 7);
            gld_lds16(A + (size_t)(row0 + h * 128 + r) * NK + kt * 64 + ls * 8,
                      (char*)As[kt & 1][h] + (size_t)(i * 512 + wid * 64) * 16);
        }
    };
    auto stageB = [&](int kt, int h){
        #pragma unroll
        for (int i = 0; i < 2; ++i){
            int p  = i * 512 + tid;
            int r  = p >> 3;
            int b  = h * 128 + r;
            int grow = (b >> 6) * 256 + m0 + (b & 63);
            int ls = (p & 7) ^ (r & 7);
            gld_lds16(Wp + (size_t)grow * KTOT + kt * 64 + ls * 8,
                      (char*)Bs[kt & 1][h] + (size_t)(i * 512 + wid * 64) * 16);
        }
    };

    f32x4 acc[8][4];
    #pragma unroll
    for (int r = 0; r < 8; ++r)
        #pragma unroll
        for (int q = 0; q < 4; ++q)
            acc[r][q] = (f32x4){0.f, 0.f, 0.f, 0.f};

    constexpr int nkt = NK / 64;
    stageA(0, 0); stageA(0, 1); stageB(0, 0);
    if (nkt > 1) stageB(1, 0);
    stageB(0, 1);

    s16x8 bfr[2][2];

    #pragma unroll
    for (int t = 0; t < nkt; ++t){
        const unsigned short* Ab = As[t & 1][wm];
        const unsigned short* Bb0 = Bs[t & 1][0];
        const unsigned short* Bb1 = Bs[t & 1][1];

        if (t + 1 < nkt) { asm volatile("s_waitcnt vmcnt(4)" ::: "memory"); }
        else             { asm volatile("s_waitcnt vmcnt(2)" ::: "memory"); }
        __builtin_amdgcn_s_barrier();
        asm volatile("" ::: "memory");

        #pragma unroll
        for (int rh = 0; rh < 2; ++rh){
            s16x8 a[4][2];
            #pragma unroll
            for (int j = 0; j < 4; ++j)
                #pragma unroll
                for (int ks = 0; ks < 2; ++ks){
                    int kb = (((ks * 4 + (lane >> 4)) ^ (lane & 7))) * 8;
                    a[j][ks] = *(const s16x8*)(Ab + (size_t)(rh * 64 + j * 16 + (lane & 15)) * 64 + kb);
                }
            if (rh == 0){
                #pragma unroll
                for (int q2 = 0; q2 < 2; ++q2)
                    #pragma unroll
                    for (int ks = 0; ks < 2; ++ks){
                        int kb = (((ks * 4 + (lane >> 4)) ^ (lane & 7))) * 8;
                        bfr[q2][ks] = *(const s16x8*)(Bb0 + (size_t)(q2 * 64 + wn * 16 + (lane & 15)) * 64 + kb);
                    }
                if (t + 1 < nkt) stageA(t + 1, 0);
            } else {
                if (t + 1 < nkt) stageA(t + 1, 1);
            }
            __builtin_amdgcn_s_setprio(1);
            #pragma unroll
            for (int j = 0; j < 4; ++j)
                #pragma unroll
                for (int q2 = 0; q2 < 2; ++q2)
                    #pragma unroll
                    for (int ks = 0; ks < 2; ++ks)
                        acc[rh * 4 + j][q2] = __builtin_amdgcn_mfma_f32_16x16x32_bf16(
                            a[j][ks], bfr[q2][ks], acc[rh * 4 + j][q2], 0, 0, 0);
            __builtin_amdgcn_s_setprio(0);
        }

        if (t + 1 < nkt) { asm volatile("s_waitcnt vmcnt(4)" ::: "memory"); }
        else             { asm volatile("s_waitcnt vmcnt(0)" ::: "memory"); }
        __builtin_amdgcn_s_barrier();
        asm volatile("" ::: "memory");

        #pragma unroll
        for (int rh = 0; rh < 2; ++rh){
            s16x8 a[4][2];
            #pragma unroll
            for (int j = 0; j < 4; ++j)
                #pragma unroll
                for (int ks = 0; ks < 2; ++ks){
                    int kb = (((ks * 4 + (lane >> 4)) ^ (lane & 7))) * 8;
                    a[j][ks] = *(const s16x8*)(Ab + (size_t)(rh * 64 + j * 16 + (lane & 15)) * 64 + kb);
                }
            if (rh == 0){
                #pragma unroll
                for (int q2 = 0; q2 < 2; ++q2)
                    #pragma unroll
                    for (int ks = 0; ks < 2; ++ks){
                        int kb = (((ks * 4 + (lane >> 4)) ^ (lane & 7))) * 8;
                        bfr[q2][ks] = *(const s16x8*)(Bb1 + (size_t)(q2 * 64 + wn * 16 + (lane & 15)) * 64 + kb);
                    }
                if (t + 2 < nkt) stageB(t + 2, 0);
            } else {
                if (t + 1 < nkt) stageB(t + 1, 1);
            }
            __builtin_amdgcn_s_setprio(1);
            #pragma unroll
            for (int j = 0; j < 4; ++j)
                #pragma unroll
                for (int q2 = 0; q2 < 2; ++q2)
                    #pragma unroll
                    for (int ks = 0; ks < 2; ++ks)
                        acc[rh * 4 + j][2 + q2] = __builtin_amdgcn_mfma_f32_16x16x32_bf16(
                            a[j][ks], bfr[q2][ks], acc[rh * 4 + j][2 + q2], 0, 0, 0);
            __builtin_amdgcn_s_setprio(0);
        }
        __builtin_amdgcn_s_barrier();
        asm volatile("" ::: "memory");
    }

    const float b0 = bp[0 * 256 + mg];
    const float b1 = bp[1 * 256 + mg];
    const float b2 = bp[2 * 256 + mg];
    const float b3 = bp[3 * 256 + mg];
    #pragma unroll
    for (int r = 0; r < 8; ++r){
        const int base = row0 + wm * 128 + r * 16 + (lane >> 4) * 4;
        float cpre[4];
        #pragma unroll
        for (int e = 0; e < 4; ++e)
            cpre[e] = csum_in[(size_t)(base + e) * MEM + mg];
        float cn[4], hn[4];
        #pragma unroll
        for (int e = 0; e < 4; ++e){
            float iv = acc[r][0][e] + b0;
            float fv = acc[r][1][e] + b1;
            float gv = acc[r][2][e] + b2;
            float ov = acc[r][3][e] + b3;
            float c  = fsigm(fv) * cpre[e] + fsigm(iv) * ftanh(gv);
            cn[e] = c;
            hn[e] = fsigm(ov) * ftanh(c);
        }
        int p0 = base >> 1;
        A_next[(size_t)p0 * KTOT + IN_DIM + mg] = f2bf(hn[0] + hn[1]);
        csum_out[(size_t)p0 * MEM + mg] = cn[0] + cn[1];
        A_next[(size_t)(p0 + 1) * KTOT + IN_DIM + mg] = f2bf(hn[2] + hn[3]);
        csum_out[(size_t)(p0 + 1) * MEM + mg] = cn[2] + cn[3];
    }

    if constexpr (PACKX){
        const int TG = 32767 * 16;
        const int bid = blockIdx.y * gridDim.x + blockIdx.x;
        const int stride_g = gridDim.x * gridDim.y * 512;
        for (int g = bid * 512 + tid; g < TG; g += stride_g){
            int i  = g >> 4;
            int ko = (g & 15) * 8;
            int l  = 31 - __clz(i + 1);
            int j  = i + 1 - (1 << l);
            size_t dst = offA(l) + (size_t)j * KTOT + ko;
            const f32x4* s = (const f32x4*)(xsrc + (size_t)i * IN_DIM + ko);
            f32x4 v0 = s[0], v1 = s[1];
            s16x8 o;
            #pragma unroll
            for (int e = 0; e < 4; ++e){ o[e] = (short)f2bf(v0[e]); o[4+e] = (short)f2bf(v1[e]); }
            *(s16x8*)(arena + dst) = o;
        }
    }
}

// ================= proven GEMM + LSTM + pair-sum, templated + leaf-DCE + PACKX(level-15 x) =================
#define KC 64

template<int NK, int RB, bool LEAF, bool PACKX>
__global__ __launch_bounds__(256) void gemm_lstm_kernel(
    const unsigned short* __restrict__ A, int n,
    const unsigned short* __restrict__ Wp, const float* __restrict__ bp,
    const float* __restrict__ csum_in,
    unsigned short* __restrict__ A_next, float* __restrict__ csum_out,
    const float* __restrict__ xsrc, unsigned short* __restrict__ arena)
{
    constexpr int BM = RB * 32;
    __shared__ __align__(16) unsigned short As[2][BM * KC];
    __shared__ __align__(16) unsigned short Bs[2][128 * KC];

    const int tid  = threadIdx.x;
    const int lane = tid & 63;
    const int wid  = tid >> 6;
    const int wm   = wid >> 1;
    const int wc   = wid & 1;
    const int row0 = blockIdx.x * BM;
    const int m0   = blockIdx.y * 32;

    const int srow = lane >> 3;
    const int scol = ((lane & 7) ^ srow) * 8;

    const int mg = m0 + wc * 16 + (lane & 15);

    const float b0 = bp[0 * 256 + mg];
    const float b1 = LEAF ? 0.f : bp[1 * 256 + mg];
    const float b2 = bp[2 * 256 + mg];
    const float b3 = bp[3 * 256 + mg];
    float cpre[RB][4];
    if (!LEAF){
        #pragma unroll
        for (int r = 0; r < RB; ++r){
            const int base = row0 + wm * (RB * 16) + r * 16 + (lane >> 4) * 4;
            #pragma unroll
            for (int e = 0; e < 4; ++e)
                cpre[r][e] = csum_in[(size_t)(base + e) * MEM + mg];
        }
    }

    f32x4 acc[RB][4];
    #pragma unroll
    for (int r = 0; r < RB; ++r)
        #pragma unroll
        for (int q = 0; q < 4; ++q)
            acc[r][q] = (f32x4){0.f, 0.f, 0.f, 0.f};

    auto stage = [&](int d, int kk){
        char* asb = (char*)As[d];
        char* bsb = (char*)Bs[d];
        #pragma unroll
        for (int q = 0; q < RB; ++q){
            int t = wid * RB + q;
            int r = t * 8 + srow;
            gld_lds16(A + (size_t)(row0 + r) * NK + kk + scol, asb + t * 1024);
        }
        #pragma unroll
        for (int q = 0; q < 4; ++q){
            int t = wid * 4 + q;
            int b = t * 8 + srow;
            int grow = (b >> 5) * 256 + m0 + (b & 31);
            gld_lds16(Wp + (size_t)grow * KTOT + kk + scol, bsb + t * 1024);
        }
    };

    constexpr int nIter = NK / KC;
    stage(0, 0);
    int buf = 0;
    #pragma unroll
    for (int it = 0; it < nIter; ++it){
        if (it + 1 < nIter){
            stage(buf ^ 1, (it + 1) * KC);
            if constexpr (RB == 4) asm volatile("s_waitcnt vmcnt(8)" ::: "memory");
            else                   asm volatile("s_waitcnt vmcnt(6)" ::: "memory");
        } else {
            asm volatile("s_waitcnt vmcnt(0)" ::: "memory");
        }
        __builtin_amdgcn_s_barrier();
        const unsigned short* Ab = As[buf];
        const unsigned short* Bb = Bs[buf];
        #pragma unroll
        for (int ks = 0; ks < 2; ++ks){
            const int slot = ks * 4 + (lane >> 4);
            const int kb = (slot ^ (lane & 7)) * 8;
            s16x8 a[RB], b[4];
            #pragma unroll
            for (int r = 0; r < RB; ++r)
                a[r] = *(const s16x8*)(Ab + (wm * (RB * 16) + r * 16 + (lane & 15)) * KC + kb);
            #pragma unroll
            for (int q = 0; q < 4; ++q)
                b[q] = *(const s16x8*)(Bb + (q * 32 + wc * 16 + (lane & 15)) * KC + kb);
            #pragma unroll
            for (int r = 0; r < RB; ++r)
                #pragma unroll
                for (int q = 0; q < 4; ++q)
                    acc[r][q] = __builtin_amdgcn_mfma_f32_16x16x32_bf16(a[r], b[q], acc[r][q], 0, 0, 0);
        }
        __builtin_amdgcn_s_barrier();
        buf ^= 1;
    }

    #pragma unroll
    for (int r = 0; r < RB; ++r){
        const int base = row0 + wm * (RB * 16) + r * 16 + (lane >> 4) * 4;
        float cn[4], hn[4];
        #pragma unroll
        for (int e = 0; e < 4; ++e){
            float iv = acc[r][0][e] + b0;
            float gv = acc[r][2][e] + b2;
            float ov = acc[r][3][e] + b3;
            float c;
            if (LEAF){
                c = fsigm(iv) * ftanh(gv);
            } else {
                float fv = acc[r][1][e] + b1;
                c = fsigm(fv) * cpre[r][e] + fsigm(iv) * ftanh(gv);
            }
            cn[e] = c;
            hn[e] = fsigm(ov) * ftanh(c);
        }
        if (base < n){
            int p0 = base >> 1;
            A_next[(size_t)p0 * KTOT + IN_DIM + mg] = f2bf(hn[0] + hn[1]);
            csum_out[(size_t)p0 * MEM + mg] = cn[0] + cn[1];
        }
        if (base + 2 < n){
            int p1 = (base >> 1) + 1;
            A_next[(size_t)p1 * KTOT + IN_DIM + mg] = f2bf(hn[2] + hn[3]);
            csum_out[(size_t)p1 * MEM + mg] = cn[2] + cn[3];
        }
    }

    if constexpr (PACKX){
        const int TG = 32768 * 16;
        const int bid = blockIdx.y * gridDim.x + blockIdx.x;
        const int stride_g = gridDim.x * gridDim.y * 256;
        for (int g = bid * 256 + tid; g < TG; g += stride_g){
            int i  = 32767 + (g >> 4);
            int ko = (g & 15) * 8;
            size_t dst = offA(15) + (size_t)(i - 32767) * KTOT + ko;
            const f32x4* s = (const f32x4*)(xsrc + (size_t)i * IN_DIM + ko);
            f32x4 v0 = s[0], v1 = s[1];
            s16x8 o;
            #pragma unroll
            for (int e = 0; e < 4; ++e){ o[e] = (short)f2bf(v0[e]); o[4+e] = (short)f2bf(v1[e]); }
            *(s16x8*)(arena + dst) = o;
        }
    }
}

// ---------------- tail: l=7..6 with 8-block grid barrier; l=5..0 + FC on block 0 alone
// (single-block levels need only vmcnt(0)+__syncthreads; Wp read directly from global/L2)
__global__ __launch_bounds__(512) void tail_kernel(
    const unsigned short* __restrict__ arena,
    const unsigned short* __restrict__ Wp, const float* __restrict__ bp,
    float* cs_in, float* cs_out,
    float* __restrict__ c_root,
    const float* __restrict__ W_fc, const float* __restrict__ b_fc,
    float* __restrict__ out, unsigned* __restrict__ ctr)
{
    __shared__ __align__(16) unsigned short WpL[128 * KTOT];   // 96 KB
    __shared__ __align__(16) unsigned short AL[64 * KTOT];     // 48 KB

    const int tid  = threadIdx.x;
    const int lane = tid & 63;
    const int wid  = tid >> 6;        // 0..7
    const int wm   = wid >> 1;        // 0..3: 16-row fragment (8-block phase)
    const int wc   = wid & 1;         // mem 16-half (8-block phase)
    const int m0   = blockIdx.x * 32;
    const int mg   = m0 + wc * 16 + (lane & 15);

    #pragma unroll
    for (int i = 0; i < 12; ++i){
        int p0 = wid * 768 + i * 64;
        int p  = p0 + lane;
        int lrow  = p / 48;
        int pslot = p % 48;
        int lslot = pslot ^ (lrow & 7);
        int grow  = (lrow >> 5) * 256 + m0 + (lrow & 31);
        gld_lds16(Wp + (size_t)grow * KTOT + lslot * 8, (char*)WpL + (size_t)p0 * 16);
    }

    const float b0 = bp[0 * 256 + mg];
    const float b1 = bp[1 * 256 + mg];
    const float b2 = bp[2 * 256 + mg];
    const float b3 = bp[3 * 256 + mg];

    asm volatile("s_waitcnt vmcnt(0)" ::: "memory");
    __builtin_amdgcn_s_barrier();

    unsigned gen = 0;
    for (int l = 7; l >= 6; --l){
        const int n = 1 << l;
        const unsigned short* Al = arena + offA(l);
        const int nhalf = (n > 64) ? (n >> 6) : 1;

        for (int h = 0; h < nhalf; ++h){
            const int r0 = h * 64;
            const int rows = 64;

            const int nslots = rows * 48;
            for (int t = 0; t * 512 < nslots; ++t){
                int pbase = t * 512 + wid * 64;
                int p = pbase + lane;
                if (p < nslots){
                    int row   = p / 48;
                    int pslot = p - row * 48;
                    int lslot = pslot ^ (row & 7);
                    gld_lds16_dev(Al + (size_t)(r0 + row) * KTOT + lslot * 8,
                                  (char*)AL + (size_t)pbase * 16);
                }
            }

            const int base = r0 + wm * 16 + (lane >> 4) * 4;
            float cpre[4];
            #pragma unroll
            for (int e = 0; e < 4; ++e)
                cpre[e] = __hip_atomic_load(&cs_in[(size_t)(base + e) * MEM + mg],
                                            __ATOMIC_RELAXED, __HIP_MEMORY_SCOPE_AGENT);

            asm volatile("s_waitcnt vmcnt(0)" ::: "memory");
            __builtin_amdgcn_s_barrier();

            f32x4 acc[4];
            #pragma unroll
            for (int q = 0; q < 4; ++q)
                acc[q] = (f32x4){0.f, 0.f, 0.f, 0.f};

            #pragma unroll
            for (int kc = 0; kc < 12; ++kc){
                const int ls = kc * 4 + (lane >> 4);
                const int kb = (ls ^ (lane & 7)) * 8;
                s16x8 a = *(const s16x8*)(AL + (size_t)(wm * 16 + (lane & 15)) * KTOT + kb);
                s16x8 b[4];
                #pragma unroll
                for (int q = 0; q < 4; ++q)
                    b[q] = *(const s16x8*)(WpL + (q * 32 + wc * 16 + (lane & 15)) * KTOT + kb);
                #pragma unroll
                for (int q = 0; q < 4; ++q)
                    acc[q] = __builtin_amdgcn_mfma_f32_16x16x32_bf16(a, b[q], acc[q], 0, 0, 0);
            }

            {
                float cn[4], hn[4];
                #pragma unroll
                for (int e = 0; e < 4; ++e){
                    float iv = acc[0][e] + b0;
                    float fv = acc[1][e] + b1;
                    float gv = acc[2][e] + b2;
                    float ov = acc[3][e] + b3;
                    float c  = fsigm(fv) * cpre[e] + fsigm(iv) * ftanh(gv);
                    cn[e] = c;
                    hn[e] = fsigm(ov) * ftanh(c);
                }
                unsigned short* A_next = (unsigned short*)arena + offA(l - 1);
                if (base < n){
                    int p0 = base >> 1;
                    st16_dev(&A_next[(size_t)p0 * KTOT + IN_DIM + mg], f2bf(hn[0] + hn[1]));
                    st32_dev(&cs_out[(size_t)p0 * MEM + mg], cn[0] + cn[1]);
                }
                if (base + 2 < n){
                    int p1 = (base >> 1) + 1;
                    st16_dev(&A_next[(size_t)p1 * KTOT + IN_DIM + mg], f2bf(hn[2] + hn[3]));
                    st32_dev(&cs_out[(size_t)p1 * MEM + mg], cn[2] + cn[3]);
                }
            }
            __builtin_amdgcn_s_barrier();
        }

        float* t = cs_in; cs_in = cs_out; cs_out = t;
        ++gen;
        grid_barrier_nf(ctr, (unsigned)(NBLK_TAIL * gen));
    }

    if (blockIdx.x != 0) return;

    // ======== single-block levels 5..0: wave wid owns mem cols [wid*32, wid*32+32) ========
    for (int l = 5; l >= 0; --l){
        const int n = 1 << l;
        const unsigned short* Al = arena + offA(l);

        // stage A rows [0,n) -> AL (device-coherent, slot-XOR pre-swizzled source)
        const int nslots = n * 48;
        {
            int pbase = wid * 64;
            int p = pbase + lane;
            // nslots <= 32*48 = 1536 -> at most 3 passes of 512
            for (int t = 0; t * 512 < nslots; ++t){
                int pb = t * 512 + pbase;
                int pp = t * 512 + p;
                if (pp < nslots){
                    int row   = pp / 48;
                    int pslot = pp - row * 48;
                    int lslot = pslot ^ (row & 7);
                    gld_lds16_dev(Al + (size_t)row * KTOT + lslot * 8,
                                  (char*)AL + (size_t)pb * 16);
                }
            }
        }

        // csum prefetch: [rf][cg][e]
        float cpre[2][2][4];
        #pragma unroll
        for (int rf = 0; rf < 2; ++rf){
            #pragma unroll
            for (int cg = 0; cg < 2; ++cg){
                const int base = rf * 16 + (lane >> 4) * 4;
                const int mgx  = wid * 32 + cg * 16 + (lane & 15);
                #pragma unroll
                for (int e = 0; e < 4; ++e)
                    cpre[rf][cg][e] = __hip_atomic_load(&cs_in[(size_t)(base + e) * MEM + mgx],
                                                        __ATOMIC_RELAXED, __HIP_MEMORY_SCOPE_AGENT);
            }
        }

        asm volatile("s_waitcnt vmcnt(0)" ::: "memory");
        __syncthreads();

        f32x4 acc[2][2][4];
        #pragma unroll
        for (int rf = 0; rf < 2; ++rf)
            #pragma unroll
            for (int cg = 0; cg < 2; ++cg)
                #pragma unroll
                for (int g = 0; g < 4; ++g)
                    acc[rf][cg][g] = (f32x4){0.f, 0.f, 0.f, 0.f};

        const int nrf = (n > 16) ? 2 : 1;
        #pragma unroll
        for (int kc = 0; kc < 12; ++kc){
            const int ls = kc * 4 + (lane >> 4);
            const int kb = (ls ^ (lane & 7)) * 8;   // swizzled LDS slot
            const int kk = ls * 8;                   // linear global offset
            s16x8 a[2];
            a[0] = *(const s16x8*)(AL + (size_t)(lane & 15) * KTOT + kb);
            if (nrf > 1)
                a[1] = *(const s16x8*)(AL + (size_t)(16 + (lane & 15)) * KTOT + kb);
            s16x8 b[2][4];
            #pragma unroll
            for (int cg = 0; cg < 2; ++cg)
                #pragma unroll
                for (int g = 0; g < 4; ++g)
                    b[cg][g] = *(const s16x8*)(Wp + (size_t)(g * 256 + wid * 32 + cg * 16 + (lane & 15)) * KTOT + kk);
            #pragma unroll
            for (int cg = 0; cg < 2; ++cg)
                #pragma unroll
                for (int g = 0; g < 4; ++g){
                    acc[0][cg][g] = __builtin_amdgcn_mfma_f32_16x16x32_bf16(a[0], b[cg][g], acc[0][cg][g], 0, 0, 0);
                    if (nrf > 1)
                        acc[1][cg][g] = __builtin_amdgcn_mfma_f32_16x16x32_bf16(a[1], b[cg][g], acc[1][cg][g], 0, 0, 0);
                }
        }

        // epilogue
        #pragma unroll
        for (int rf = 0; rf < 2; ++rf){
            if (rf >= nrf) break;
            #pragma unroll
            for (int cg = 0; cg < 2; ++cg){
                const int base = rf * 16 + (lane >> 4) * 4;
                const int mgx  = wid * 32 + cg * 16 + (lane & 15);
                const float bb0 = bp[0 * 256 + mgx];
                const float bb1 = bp[1 * 256 + mgx];
                const float bb2 = bp[2 * 256 + mgx];
                const float bb3 = bp[3 * 256 + mgx];
                float cn[4], hn[4];
                #pragma unroll
                for (int e = 0; e < 4; ++e){
                    float iv = acc[rf][cg][0][e] + bb0;
                    float fv = acc[rf][cg][1][e] + bb1;
                    float gv = acc[rf][cg][2][e] + bb2;
                    float ov = acc[rf][cg][3][e] + bb3;
                    float c  = fsigm(fv) * cpre[rf][cg][e] + fsigm(iv) * ftanh(gv);
                    cn[e] = c;
                    hn[e] = fsigm(ov) * ftanh(c);
                }
                if (l == 0){
                    if (base == 0) st32_dev(&c_root[mgx], cn[0]);
                } else {
                    unsigned short* A_next = (unsigned short*)arena + offA(l - 1);
                    if (base < n){
                        int p0 = base >> 1;
                        st16_dev(&A_next[(size_t)p0 * KTOT + IN_DIM + mgx], f2bf(hn[0] + hn[1]));
                        st32_dev(&cs_out[(size_t)p0 * MEM + mgx], cn[0] + cn[1]);
                    }
                    if (base + 2 < n){
                        int p1 = (base >> 1) + 1;
                        st16_dev(&A_next[(size_t)p1 * KTOT + IN_DIM + mgx], f2bf(hn[2] + hn[3]));
                        st32_dev(&cs_out[(size_t)p1 * MEM + mgx], cn[2] + cn[3]);
                    }
                }
            }
        }

        float* t = cs_in; cs_in = cs_out; cs_out = t;
        asm volatile("s_waitcnt vmcnt(0)" ::: "memory");
        __syncthreads();
    }

    // FC: c_root written by this block (sc0sc1), drained above
    if (wid < 4){
        int w = wid;
        for (int cls = w * 3; cls < w * 3 + 3; ++cls){
            float s = 0.f;
            for (int m = lane; m < 256; m += 64){
                float cr = __hip_atomic_load(&c_root[m], __ATOMIC_RELAXED, __HIP_MEMORY_SCOPE_AGENT);
                s += cr * W_fc[cls * 256 + m];
            }
            #pragma unroll
            for (int off = 32; off; off >>= 1)
                s += __shfl_down(s, off, 64);
            if (lane == 0) out[cls] = s + b_fc[cls];
        }
    }
}

extern "C" void kernel_launch(void* const* d_in, const int* in_sizes, int n_in,
                              void* d_out, int out_size, void* d_ws, size_t ws_size,
                              hipStream_t stream)
{
    const float* x    = (const float*)d_in[0];
    const float* W_ih = (const float*)d_in[1];
    const float* b_ih = (const float*)d_in[2];
    const float* W_hh = (const float*)d_in[3];
    const float* b_hh = (const float*)d_in[4];
    const float* W_fc = (const float*)d_in[5];
    const float* b_fc = (const float*)d_in[6];
    float* out = (float*)d_out;

    const size_t OFF_WP = 0;
    const size_t OFF_BP = 786432;
    const size_t OFF_A  = 790528;
    const size_t OFF_CS0 = OFF_A + (size_t)(ARENA_ELEMS + ARENA_PAD) * 2;
    const size_t OFF_CS1 = OFF_CS0 + 33554432;
    const size_t OFF_CR  = OFF_CS1 + 33554432;
    const size_t OFF_CTR = OFF_CR + 1024;
    const size_t NEEDED  = OFF_CTR + 64;
    if (ws_size < NEEDED) return;

    char* ws = (char*)d_ws;
    unsigned short* Wp    = (unsigned short*)(ws + OFF_WP);
    float* bp             = (float*)(ws + OFF_BP);
    unsigned short* arena = (unsigned short*)(ws + OFF_A);
    float* cs0            = (float*)(ws + OFF_CS0);
    float* cs1            = (float*)(ws + OFF_CS1);
    float* c_root         = (float*)(ws + OFF_CR);
    unsigned* ctr         = (unsigned*)(ws + OFF_CTR);

    pack_kernel<<<dim3(2048), dim3(256), 0, stream>>>(
        x, W_ih, b_ih, W_hh, b_hh, Wp, bp, arena, ctr);

    // ---- leaf (l=16): RB=4 + LEAF-DCE + fused LEVEL-15 x pack
    gemm_lstm_kernel<IN_DIM, 4, true, true><<<dim3(NLEAF / 128, 8), dim3(256), 0, stream>>>(
        arena + offA(16), NLEAF, Wp, bp,
        nullptr, arena + offA(15), cs0, x, arena);

    // ---- l=15: 8-phase + fused levels-14..0 x pack; l=14: 8-phase plain
    gemm_lstm8p_kernel<KTOT, true><<<dim3(128, 4), dim3(512), 0, stream>>>(
        arena + offA(15), 32768, Wp, bp, cs0, arena + offA(14), cs1, x, arena);
    gemm_lstm8p_kernel<KTOT, false><<<dim3(64, 4), dim3(512), 0, stream>>>(
        arena + offA(14), 16384, Wp, bp, cs1, arena + offA(13), cs0, nullptr, nullptr);

    // ---- l=13: RB=4
    gemm_lstm_kernel<KTOT, 4, false, false><<<dim3(64, 8), dim3(256), 0, stream>>>(
        arena + offA(13), 8192, Wp, bp, cs0, arena + offA(12), cs1, nullptr, nullptr);

    // ---- l=12..8: RB=2
    float* cs_in = cs1; float* cs_out = cs0;
    for (int l = 12; l >= 8; --l){
        int n = 1 << l;
        gemm_lstm_kernel<KTOT, 2, false, false><<<dim3(n / 64, 8), dim3(256), 0, stream>>>(
            arena + offA(l), n, Wp, bp,
            cs_in, arena + offA(l - 1), cs_out, nullptr, nullptr);
        float* t = cs_in; cs_in = cs_out; cs_out = t;
    }

    // ---- tail: l=7..6 (8 blocks + grid barrier), l=5..0 + FC (block 0, syncthreads only)
    tail_kernel<<<dim3(NBLK_TAIL), dim3(512), 0, stream>>>(
        arena, Wp, bp, cs_in, cs_out, c_root, W_fc, b_fc, out, ctr);
}

// Round 22
// 193.254 us; speedup vs baseline: 1.8376x; 1.8376x over previous
//
#include <hip/hip_runtime.h>
#include <hip/hip_bf16.h>
#include <cstddef>

#define IN_DIM 128
#define MEM 256
#define KTOT 384
#define NLEAF 65536
#define NBLK_TAIL 8

typedef float f32x4 __attribute__((ext_vector_type(4)));
typedef short s16x8 __attribute__((ext_vector_type(8)));
typedef unsigned int u32;

__device__ inline unsigned short f2bf(float f){
    unsigned int u = __builtin_bit_cast(unsigned int, f);
    u += 0x7fff + ((u >> 16) & 1);
    return (unsigned short)(u >> 16);
}

__device__ inline void gld_lds16(const void* g, void* l){
    __builtin_amdgcn_global_load_lds((const __attribute__((address_space(1))) u32*)g,
                                     (__attribute__((address_space(3))) u32*)l, 16, 0, 0);
}
// device-coherent (SC0|SC1): read from coherence point, bypass stale L1/L2
__device__ inline void gld_lds16_dev(const void* g, void* l){
    __builtin_amdgcn_global_load_lds((const __attribute__((address_space(1))) u32*)g,
                                     (__attribute__((address_space(3))) u32*)l, 16, 0, 17);
}
// write-through device-coherent stores
__device__ inline void st16_dev(unsigned short* p, unsigned short v){
    unsigned int vv = v;
    asm volatile("global_store_short %0, %1, off sc0 sc1" :: "v"(p), "v"(vv) : "memory");
}
__device__ inline void st32_dev(float* p, float v){
    asm volatile("global_store_dword %0, %1, off sc0 sc1" :: "v"(p), "v"(v) : "memory");
}

__device__ inline float fsigm(float x){
    return __builtin_amdgcn_rcpf(1.f + __expf(-x));
}
__device__ inline float ftanh(float x){
    return 2.f * __builtin_amdgcn_rcpf(1.f + __expf(-2.f * x)) - 1.f;
}

// A-arena element offsets: leaf (l=16) at 0, stride 128; levels 15..0 stride 384.
__host__ __device__ inline size_t offA(int l){
    if (l == 16) return 0;
    return 8388608u + 384u * (65536u - (1u << (l + 1)));
}
#define ARENA_ELEMS 33554048u
#define ARENA_PAD   65536u

// FENCE-FREE grid barrier (8 co-resident blocks).
__device__ inline void grid_barrier_nf(unsigned* ctr, unsigned target){
    asm volatile("s_waitcnt vmcnt(0)" ::: "memory");
    __syncthreads();
    if (threadIdx.x == 0){
        __hip_atomic_fetch_add(ctr, 1u, __ATOMIC_RELAXED, __HIP_MEMORY_SCOPE_AGENT);
        while (__hip_atomic_load(ctr, __ATOMIC_RELAXED, __HIP_MEMORY_SCOPE_AGENT) < target)
            __builtin_amdgcn_s_sleep(2);
    }
    __syncthreads();
}

// ---------------- pack: W (+bias, +ctr reset) and LEAF x rows only
__global__ void pack_kernel(const float* __restrict__ x,
                            const float* __restrict__ W_ih, const float* __restrict__ b_ih,
                            const float* __restrict__ W_hh, const float* __restrict__ b_hh,
                            unsigned short* __restrict__ Wp, float* __restrict__ bp,
                            unsigned short* __restrict__ Aarena, unsigned* __restrict__ ctr){
    const int stride = gridDim.x * blockDim.x;
    const int tid0 = blockIdx.x * blockDim.x + threadIdx.x;
    if (tid0 == 0){ ctr[0] = 0; }

    for (int g = tid0; g < 1024 * 48; g += stride){
        int row = g / 48, ko = (g - row * 48) * 8;
        const float* s = (ko < IN_DIM) ? (W_ih + (size_t)row * IN_DIM + ko)
                                       : (W_hh + (size_t)row * MEM + (ko - IN_DIM));
        f32x4 v0 = *(const f32x4*)s, v1 = *(const f32x4*)(s + 4);
        s16x8 o;
        #pragma unroll
        for (int e = 0; e < 4; ++e){ o[e] = (short)f2bf(v0[e]); o[4+e] = (short)f2bf(v1[e]); }
        *(s16x8*)(Wp + (size_t)row * KTOT + ko) = o;
        if (ko == 0) bp[row] = b_ih[row] + b_hh[row];
    }

    const int TOTAL_G = 65536 * 16;
    for (int g = tid0; g < TOTAL_G; g += stride){
        int j  = g >> 4;
        int ko = (g & 15) * 8;
        const f32x4* s = (const f32x4*)(x + (size_t)(65535 + j) * IN_DIM + ko);
        f32x4 v0 = s[0], v1 = s[1];
        s16x8 o;
        #pragma unroll
        for (int e = 0; e < 4; ++e){ o[e] = (short)f2bf(v0[e]); o[4+e] = (short)f2bf(v1[e]); }
        *(s16x8*)(Aarena + (size_t)j * IN_DIM + ko) = o;
    }
}

// ================= 8-phase-style 256-row GEMM + LSTM + pair-sum (l15, l14) =================
template<int NK, bool PACKX>
__global__ __launch_bounds__(512, 1) void gemm_lstm8p_kernel(
    const unsigned short* __restrict__ A, int n,
    const unsigned short* __restrict__ Wp, const float* __restrict__ bp,
    const float* __restrict__ csum_in,
    unsigned short* __restrict__ A_next, float* __restrict__ csum_out,
    const float* __restrict__ xsrc, unsigned short* __restrict__ arena)
{
    __shared__ __align__(16) unsigned short As[2][2][128 * 64];   // [buf][half] 64 KB
    __shared__ __align__(16) unsigned short Bs[2][2][128 * 64];   // 64 KB

    const int tid  = threadIdx.x;
    const int lane = tid & 63;
    const int wid  = tid >> 6;        // 0..7
    const int wm   = wid >> 2;        // A row-half (128 rows)
    const int wn   = wid & 3;         // mem 16-col group
    const int row0 = blockIdx.x * 256;
    const int m0   = blockIdx.y * 64;
    const int mg   = m0 + wn * 16 + (lane & 15);

    auto stageA = [&](int kt, int h){
        #pragma unroll
        for (int i = 0; i < 2; ++i){
            int p  = i * 512 + tid;
            int r  = p >> 3;
            int ls = (p & 7) ^ (r & 7);
            gld_lds16(A + (size_t)(row0 + h * 128 + r) * NK + kt * 64 + ls * 8,
                      (char*)As[kt & 1][h] + (size_t)(i * 512 + wid * 64) * 16);
        }
    };
    auto stageB = [&](int kt, int h){
        #pragma unroll
        for (int i = 0; i < 2; ++i){
            int p  = i * 512 + tid;
            int r  = p >> 3;
            int b  = h * 128 + r;
            int grow = (b >> 6) * 256 + m0 + (b & 63);
            int ls = (p & 7) ^ (r & 7);
            gld_lds16(Wp + (size_t)grow * KTOT + kt * 64 + ls * 8,
                      (char*)Bs[kt & 1][h] + (size_t)(i * 512 + wid * 64) * 16);
        }
    };

    f32x4 acc[8][4];
    #pragma unroll
    for (int r = 0; r < 8; ++r)
        #pragma unroll
        for (int q = 0; q < 4; ++q)
            acc[r][q] = (f32x4){0.f, 0.f, 0.f, 0.f};

    constexpr int nkt = NK / 64;
    stageA(0, 0); stageA(0, 1); stageB(0, 0);
    if (nkt > 1) stageB(1, 0);
    stageB(0, 1);

    s16x8 bfr[2][2];

    #pragma unroll
    for (int t = 0; t < nkt; ++t){
        const unsigned short* Ab = As[t & 1][wm];
        const unsigned short* Bb0 = Bs[t & 1][0];
        const unsigned short* Bb1 = Bs[t & 1][1];

        if (t + 1 < nkt) { asm volatile("s_waitcnt vmcnt(4)" ::: "memory"); }
        else             { asm volatile("s_waitcnt vmcnt(2)" ::: "memory"); }
        __builtin_amdgcn_s_barrier();
        asm volatile("" ::: "memory");

        #pragma unroll
        for (int rh = 0; rh < 2; ++rh){
            s16x8 a[4][2];
            #pragma unroll
            for (int j = 0; j < 4; ++j)
                #pragma unroll
                for (int ks = 0; ks < 2; ++ks){
                    int kb = (((ks * 4 + (lane >> 4)) ^ (lane & 7))) * 8;
                    a[j][ks] = *(const s16x8*)(Ab + (size_t)(rh * 64 + j * 16 + (lane & 15)) * 64 + kb);
                }
            if (rh == 0){
                #pragma unroll
                for (int q2 = 0; q2 < 2; ++q2)
                    #pragma unroll
                    for (int ks = 0; ks < 2; ++ks){
                        int kb = (((ks * 4 + (lane >> 4)) ^ (lane & 7))) * 8;
                        bfr[q2][ks] = *(const s16x8*)(Bb0 + (size_t)(q2 * 64 + wn * 16 + (lane & 15)) * 64 + kb);
                    }
                if (t + 1 < nkt) stageA(t + 1, 0);
            } else {
                if (t + 1 < nkt) stageA(t + 1, 1);
            }
            __builtin_amdgcn_s_setprio(1);
            #pragma unroll
            for (int j = 0; j < 4; ++j)
                #pragma unroll
                for (int q2 = 0; q2 < 2; ++q2)
                    #pragma unroll
                    for (int ks = 0; ks < 2; ++ks)
                        acc[rh * 4 + j][q2] = __builtin_amdgcn_mfma_f32_16x16x32_bf16(
                            a[j][ks], bfr[q2][ks], acc[rh * 4 + j][q2], 0, 0, 0);
            __builtin_amdgcn_s_setprio(0);
        }

        if (t + 1 < nkt) { asm volatile("s_waitcnt vmcnt(4)" ::: "memory"); }
        else             { asm volatile("s_waitcnt vmcnt(0)" ::: "memory"); }
        __builtin_amdgcn_s_barrier();
        asm volatile("" ::: "memory");

        #pragma unroll
        for (int rh = 0; rh < 2; ++rh){
            s16x8 a[4][2];
            #pragma unroll
            for (int j = 0; j < 4; ++j)
                #pragma unroll
                for (int ks = 0; ks < 2; ++ks){
                    int kb = (((ks * 4 + (lane >> 4)) ^ (lane & 7))) * 8;
                    a[j][ks] = *(const s16x8*)(Ab + (size_t)(rh * 64 + j * 16 + (lane & 15)) * 64 + kb);
                }
            if (rh == 0){
                #pragma unroll
                for (int q2 = 0; q2 < 2; ++q2)
                    #pragma unroll
                    for (int ks = 0; ks < 2; ++ks){
                        int kb = (((ks * 4 + (lane >> 4)) ^ (lane & 7))) * 8;
                        bfr[q2][ks] = *(const s16x8*)(Bb1 + (size_t)(q2 * 64 + wn * 16 + (lane & 15)) * 64 + kb);
                    }
                if (t + 2 < nkt) stageB(t + 2, 0);
            } else {
                if (t + 1 < nkt) stageB(t + 1, 1);
            }
            __builtin_amdgcn_s_setprio(1);
            #pragma unroll
            for (int j = 0; j < 4; ++j)
                #pragma unroll
                for (int q2 = 0; q2 < 2; ++q2)
                    #pragma unroll
                    for (int ks = 0; ks < 2; ++ks)
                        acc[rh * 4 + j][2 + q2] = __builtin_amdgcn_mfma_f32_16x16x32_bf16(
                            a[j][ks], bfr[q2][ks], acc[rh * 4 + j][2 + q2], 0, 0, 0);
            __builtin_amdgcn_s_setprio(0);
        }
        __builtin_amdgcn_s_barrier();
        asm volatile("" ::: "memory");
    }

    const float b0 = bp[0 * 256 + mg];
    const float b1 = bp[1 * 256 + mg];
    const float b2 = bp[2 * 256 + mg];
    const float b3 = bp[3 * 256 + mg];
    #pragma unroll
    for (int r = 0; r < 8; ++r){
        const int base = row0 + wm * 128 + r * 16 + (lane >> 4) * 4;
        float cpre[4];
        #pragma unroll
        for (int e = 0; e < 4; ++e)
            cpre[e] = csum_in[(size_t)(base + e) * MEM + mg];
        float cn[4], hn[4];
        #pragma unroll
        for (int e = 0; e < 4; ++e){
            float iv = acc[r][0][e] + b0;
            float fv = acc[r][1][e] + b1;
            float gv = acc[r][2][e] + b2;
            float ov = acc[r][3][e] + b3;
            float c  = fsigm(fv) * cpre[e] + fsigm(iv) * ftanh(gv);
            cn[e] = c;
            hn[e] = fsigm(ov) * ftanh(c);
        }
        int p0 = base >> 1;
        A_next[(size_t)p0 * KTOT + IN_DIM + mg] = f2bf(hn[0] + hn[1]);
        csum_out[(size_t)p0 * MEM + mg] = cn[0] + cn[1];
        A_next[(size_t)(p0 + 1) * KTOT + IN_DIM + mg] = f2bf(hn[2] + hn[3]);
        csum_out[(size_t)(p0 + 1) * MEM + mg] = cn[2] + cn[3];
    }

    if constexpr (PACKX){
        const int TG = 32767 * 16;
        const int bid = blockIdx.y * gridDim.x + blockIdx.x;
        const int stride_g = gridDim.x * gridDim.y * 512;
        for (int g = bid * 512 + tid; g < TG; g += stride_g){
            int i  = g >> 4;
            int ko = (g & 15) * 8;
            int l  = 31 - __clz(i + 1);
            int j  = i + 1 - (1 << l);
            size_t dst = offA(l) + (size_t)j * KTOT + ko;
            const f32x4* s = (const f32x4*)(xsrc + (size_t)i * IN_DIM + ko);
            f32x4 v0 = s[0], v1 = s[1];
            s16x8 o;
            #pragma unroll
            for (int e = 0; e < 4; ++e){ o[e] = (short)f2bf(v0[e]); o[4+e] = (short)f2bf(v1[e]); }
            *(s16x8*)(arena + dst) = o;
        }
    }
}

// ================= proven GEMM + LSTM + pair-sum, templated + leaf-DCE + PACKX(level-15 x) =================
#define KC 64

template<int NK, int RB, bool LEAF, bool PACKX>
__global__ __launch_bounds__(256) void gemm_lstm_kernel(
    const unsigned short* __restrict__ A, int n,
    const unsigned short* __restrict__ Wp, const float* __restrict__ bp,
    const float* __restrict__ csum_in,
    unsigned short* __restrict__ A_next, float* __restrict__ csum_out,
    const float* __restrict__ xsrc, unsigned short* __restrict__ arena)
{
    constexpr int BM = RB * 32;
    __shared__ __align__(16) unsigned short As[2][BM * KC];
    __shared__ __align__(16) unsigned short Bs[2][128 * KC];

    const int tid  = threadIdx.x;
    const int lane = tid & 63;
    const int wid  = tid >> 6;
    const int wm   = wid >> 1;
    const int wc   = wid & 1;
    const int row0 = blockIdx.x * BM;
    const int m0   = blockIdx.y * 32;

    const int srow = lane >> 3;
    const int scol = ((lane & 7) ^ srow) * 8;

    const int mg = m0 + wc * 16 + (lane & 15);

    const float b0 = bp[0 * 256 + mg];
    const float b1 = LEAF ? 0.f : bp[1 * 256 + mg];
    const float b2 = bp[2 * 256 + mg];
    const float b3 = bp[3 * 256 + mg];
    float cpre[RB][4];
    if (!LEAF){
        #pragma unroll
        for (int r = 0; r < RB; ++r){
            const int base = row0 + wm * (RB * 16) + r * 16 + (lane >> 4) * 4;
            #pragma unroll
            for (int e = 0; e < 4; ++e)
                cpre[r][e] = csum_in[(size_t)(base + e) * MEM + mg];
        }
    }

    f32x4 acc[RB][4];
    #pragma unroll
    for (int r = 0; r < RB; ++r)
        #pragma unroll
        for (int q = 0; q < 4; ++q)
            acc[r][q] = (f32x4){0.f, 0.f, 0.f, 0.f};

    auto stage = [&](int d, int kk){
        char* asb = (char*)As[d];
        char* bsb = (char*)Bs[d];
        #pragma unroll
        for (int q = 0; q < RB; ++q){
            int t = wid * RB + q;
            int r = t * 8 + srow;
            gld_lds16(A + (size_t)(row0 + r) * NK + kk + scol, asb + t * 1024);
        }
        #pragma unroll
        for (int q = 0; q < 4; ++q){
            int t = wid * 4 + q;
            int b = t * 8 + srow;
            int grow = (b >> 5) * 256 + m0 + (b & 31);
            gld_lds16(Wp + (size_t)grow * KTOT + kk + scol, bsb + t * 1024);
        }
    };

    constexpr int nIter = NK / KC;
    stage(0, 0);
    int buf = 0;
    #pragma unroll
    for (int it = 0; it < nIter; ++it){
        if (it + 1 < nIter){
            stage(buf ^ 1, (it + 1) * KC);
            if constexpr (RB == 4) asm volatile("s_waitcnt vmcnt(8)" ::: "memory");
            else                   asm volatile("s_waitcnt vmcnt(6)" ::: "memory");
        } else {
            asm volatile("s_waitcnt vmcnt(0)" ::: "memory");
        }
        __builtin_amdgcn_s_barrier();
        const unsigned short* Ab = As[buf];
        const unsigned short* Bb = Bs[buf];
        #pragma unroll
        for (int ks = 0; ks < 2; ++ks){
            const int slot = ks * 4 + (lane >> 4);
            const int kb = (slot ^ (lane & 7)) * 8;
            s16x8 a[RB], b[4];
            #pragma unroll
            for (int r = 0; r < RB; ++r)
                a[r] = *(const s16x8*)(Ab + (wm * (RB * 16) + r * 16 + (lane & 15)) * KC + kb);
            #pragma unroll
            for (int q = 0; q < 4; ++q)
                b[q] = *(const s16x8*)(Bb + (q * 32 + wc * 16 + (lane & 15)) * KC + kb);
            #pragma unroll
            for (int r = 0; r < RB; ++r)
                #pragma unroll
                for (int q = 0; q < 4; ++q)
                    acc[r][q] = __builtin_amdgcn_mfma_f32_16x16x32_bf16(a[r], b[q], acc[r][q], 0, 0, 0);
        }
        __builtin_amdgcn_s_barrier();
        buf ^= 1;
    }

    #pragma unroll
    for (int r = 0; r < RB; ++r){
        const int base = row0 + wm * (RB * 16) + r * 16 + (lane >> 4) * 4;
        float cn[4], hn[4];
        #pragma unroll
        for (int e = 0; e < 4; ++e){
            float iv = acc[r][0][e] + b0;
            float gv = acc[r][2][e] + b2;
            float ov = acc[r][3][e] + b3;
            float c;
            if (LEAF){
                c = fsigm(iv) * ftanh(gv);
            } else {
                float fv = acc[r][1][e] + b1;
                c = fsigm(fv) * cpre[r][e] + fsigm(iv) * ftanh(gv);
            }
            cn[e] = c;
            hn[e] = fsigm(ov) * ftanh(c);
        }
        if (base < n){
            int p0 = base >> 1;
            A_next[(size_t)p0 * KTOT + IN_DIM + mg] = f2bf(hn[0] + hn[1]);
            csum_out[(size_t)p0 * MEM + mg] = cn[0] + cn[1];
        }
        if (base + 2 < n){
            int p1 = (base >> 1) + 1;
            A_next[(size_t)p1 * KTOT + IN_DIM + mg] = f2bf(hn[2] + hn[3]);
            csum_out[(size_t)p1 * MEM + mg] = cn[2] + cn[3];
        }
    }

    if constexpr (PACKX){
        const int TG = 32768 * 16;
        const int bid = blockIdx.y * gridDim.x + blockIdx.x;
        const int stride_g = gridDim.x * gridDim.y * 256;
        for (int g = bid * 256 + tid; g < TG; g += stride_g){
            int i  = 32767 + (g >> 4);
            int ko = (g & 15) * 8;
            size_t dst = offA(15) + (size_t)(i - 32767) * KTOT + ko;
            const f32x4* s = (const f32x4*)(xsrc + (size_t)i * IN_DIM + ko);
            f32x4 v0 = s[0], v1 = s[1];
            s16x8 o;
            #pragma unroll
            for (int e = 0; e < 4; ++e){ o[e] = (short)f2bf(v0[e]); o[4+e] = (short)f2bf(v1[e]); }
            *(s16x8*)(arena + dst) = o;
        }
    }
}

// ---------------- tail: levels 7..0 + FC fused, 8 blocks x 512 threads, fence-free barrier
__global__ __launch_bounds__(512) void tail_kernel(
    const unsigned short* __restrict__ arena,
    const unsigned short* __restrict__ Wp, const float* __restrict__ bp,
    float* cs_in, float* cs_out,
    float* __restrict__ c_root,
    const float* __restrict__ W_fc, const float* __restrict__ b_fc,
    float* __restrict__ out, unsigned* __restrict__ ctr)
{
    __shared__ __align__(16) unsigned short WpL[128 * KTOT];   // 96 KB
    __shared__ __align__(16) unsigned short AL[64 * KTOT];     // 48 KB

    const int tid  = threadIdx.x;
    const int lane = tid & 63;
    const int wid  = tid >> 6;        // 0..7
    const int wm   = wid >> 1;        // 0..3: 16-row fragment
    const int wc   = wid & 1;         // mem 16-half
    const int m0   = blockIdx.x * 32;
    const int mg   = m0 + wc * 16 + (lane & 15);

    #pragma unroll
    for (int i = 0; i < 12; ++i){
        int p0 = wid * 768 + i * 64;
        int p  = p0 + lane;
        int lrow  = p / 48;
        int pslot = p % 48;
        int lslot = pslot ^ (lrow & 7);
        int grow  = (lrow >> 5) * 256 + m0 + (lrow & 31);
        gld_lds16(Wp + (size_t)grow * KTOT + lslot * 8, (char*)WpL + (size_t)p0 * 16);
    }

    const float b0 = bp[0 * 256 + mg];
    const float b1 = bp[1 * 256 + mg];
    const float b2 = bp[2 * 256 + mg];
    const float b3 = bp[3 * 256 + mg];

    asm volatile("s_waitcnt vmcnt(0)" ::: "memory");
    __builtin_amdgcn_s_barrier();

    unsigned gen = 0;
    for (int l = 7; l >= 0; --l){
        const int n = 1 << l;
        const unsigned short* Al = arena + offA(l);
        const int nhalf = (n > 64) ? (n >> 6) : 1;

        for (int h = 0; h < nhalf; ++h){
            const int r0 = h * 64;
            const int rows = (n < 64) ? n : 64;

            const int nslots = rows * 48;
            for (int t = 0; t * 512 < nslots; ++t){
                int pbase = t * 512 + wid * 64;
                int p = pbase + lane;
                if (p < nslots){
                    int row   = p / 48;
                    int pslot = p - row * 48;
                    int lslot = pslot ^ (row & 7);
                    gld_lds16_dev(Al + (size_t)(r0 + row) * KTOT + lslot * 8,
                                  (char*)AL + (size_t)pbase * 16);
                }
            }

            const int base = r0 + wm * 16 + (lane >> 4) * 4;
            float cpre[4];
            #pragma unroll
            for (int e = 0; e < 4; ++e)
                cpre[e] = __hip_atomic_load(&cs_in[(size_t)(base + e) * MEM + mg],
                                            __ATOMIC_RELAXED, __HIP_MEMORY_SCOPE_AGENT);

            asm volatile("s_waitcnt vmcnt(0)" ::: "memory");
            __builtin_amdgcn_s_barrier();

            f32x4 acc[4];
            #pragma unroll
            for (int q = 0; q < 4; ++q)
                acc[q] = (f32x4){0.f, 0.f, 0.f, 0.f};

            #pragma unroll
            for (int kc = 0; kc < 12; ++kc){
                const int ls = kc * 4 + (lane >> 4);
                const int kb = (ls ^ (lane & 7)) * 8;
                s16x8 a = *(const s16x8*)(AL + (size_t)(wm * 16 + (lane & 15)) * KTOT + kb);
                s16x8 b[4];
                #pragma unroll
                for (int q = 0; q < 4; ++q)
                    b[q] = *(const s16x8*)(WpL + (q * 32 + wc * 16 + (lane & 15)) * KTOT + kb);
                #pragma unroll
                for (int q = 0; q < 4; ++q)
                    acc[q] = __builtin_amdgcn_mfma_f32_16x16x32_bf16(a, b[q], acc[q], 0, 0, 0);
            }

            {
                float cn[4], hn[4];
                #pragma unroll
                for (int e = 0; e < 4; ++e){
                    float iv = acc[0][e] + b0;
                    float fv = acc[1][e] + b1;
                    float gv = acc[2][e] + b2;
                    float ov = acc[3][e] + b3;
                    float c  = fsigm(fv) * cpre[e] + fsigm(iv) * ftanh(gv);
                    cn[e] = c;
                    hn[e] = fsigm(ov) * ftanh(c);
                }
                if (l == 0){
                    if (base == 0) st32_dev(&c_root[mg], cn[0]);
                } else {
                    unsigned short* A_next = (unsigned short*)arena + offA(l - 1);
                    if (base < n){
                        int p0 = base >> 1;
                        st16_dev(&A_next[(size_t)p0 * KTOT + IN_DIM + mg], f2bf(hn[0] + hn[1]));
                        st32_dev(&cs_out[(size_t)p0 * MEM + mg], cn[0] + cn[1]);
                    }
                    if (base + 2 < n){
                        int p1 = (base >> 1) + 1;
                        st16_dev(&A_next[(size_t)p1 * KTOT + IN_DIM + mg], f2bf(hn[2] + hn[3]));
                        st32_dev(&cs_out[(size_t)p1 * MEM + mg], cn[2] + cn[3]);
                    }
                }
            }
            __builtin_amdgcn_s_barrier();
        }

        float* t = cs_in; cs_in = cs_out; cs_out = t;
        ++gen;
        grid_barrier_nf(ctr, (unsigned)(NBLK_TAIL * gen));
    }

    if (blockIdx.x == 0 && wid < 4){
        int w = wid;
        for (int cls = w * 3; cls < w * 3 + 3; ++cls){
            float s = 0.f;
            for (int m = lane; m < 256; m += 64){
                float cr = __hip_atomic_load(&c_root[m], __ATOMIC_RELAXED, __HIP_MEMORY_SCOPE_AGENT);
                s += cr * W_fc[cls * 256 + m];
            }
            #pragma unroll
            for (int off = 32; off; off >>= 1)
                s += __shfl_down(s, off, 64);
            if (lane == 0) out[cls] = s + b_fc[cls];
        }
    }
}

extern "C" void kernel_launch(void* const* d_in, const int* in_sizes, int n_in,
                              void* d_out, int out_size, void* d_ws, size_t ws_size,
                              hipStream_t stream)
{
    const float* x    = (const float*)d_in[0];
    const float* W_ih = (const float*)d_in[1];
    const float* b_ih = (const float*)d_in[2];
    const float* W_hh = (const float*)d_in[3];
    const float* b_hh = (const float*)d_in[4];
    const float* W_fc = (const float*)d_in[5];
    const float* b_fc = (const float*)d_in[6];
    float* out = (float*)d_out;

    const size_t OFF_WP = 0;
    const size_t OFF_BP = 786432;
    const size_t OFF_A  = 790528;
    const size_t OFF_CS0 = OFF_A + (size_t)(ARENA_ELEMS + ARENA_PAD) * 2;
    const size_t OFF_CS1 = OFF_CS0 + 33554432;
    const size_t OFF_CR  = OFF_CS1 + 33554432;
    const size_t OFF_CTR = OFF_CR + 1024;
    const size_t NEEDED  = OFF_CTR + 64;
    if (ws_size < NEEDED) return;

    char* ws = (char*)d_ws;
    unsigned short* Wp    = (unsigned short*)(ws + OFF_WP);
    float* bp             = (float*)(ws + OFF_BP);
    unsigned short* arena = (unsigned short*)(ws + OFF_A);
    float* cs0            = (float*)(ws + OFF_CS0);
    float* cs1            = (float*)(ws + OFF_CS1);
    float* c_root         = (float*)(ws + OFF_CR);
    unsigned* ctr         = (unsigned*)(ws + OFF_CTR);

    pack_kernel<<<dim3(2048), dim3(256), 0, stream>>>(
        x, W_ih, b_ih, W_hh, b_hh, Wp, bp, arena, ctr);

    // ---- leaf (l=16): RB=4 + LEAF-DCE + fused LEVEL-15 x pack
    gemm_lstm_kernel<IN_DIM, 4, true, true><<<dim3(NLEAF / 128, 8), dim3(256), 0, stream>>>(
        arena + offA(16), NLEAF, Wp, bp,
        nullptr, arena + offA(15), cs0, x, arena);

    // ---- l=15: 8-phase + fused levels-14..0 x pack; l=14: 8-phase plain
    gemm_lstm8p_kernel<KTOT, true><<<dim3(128, 4), dim3(512), 0, stream>>>(
        arena + offA(15), 32768, Wp, bp, cs0, arena + offA(14), cs1, x, arena);
    gemm_lstm8p_kernel<KTOT, false><<<dim3(64, 4), dim3(512), 0, stream>>>(
        arena + offA(14), 16384, Wp, bp, cs1, arena + offA(13), cs0, nullptr, nullptr);

    // ---- l=13: RB=4
    gemm_lstm_kernel<KTOT, 4, false, false><<<dim3(64, 8), dim3(256), 0, stream>>>(
        arena + offA(13), 8192, Wp, bp, cs0, arena + offA(12), cs1, nullptr, nullptr);

    // ---- l=12..8: RB=2
    float* cs_in = cs1; float* cs_out = cs0;
    for (int l = 12; l >= 8; --l){
        int n = 1 << l;
        gemm_lstm_kernel<KTOT, 2, false, false><<<dim3(n / 64, 8), dim3(256), 0, stream>>>(
            arena + offA(l), n, Wp, bp,
            cs_in, arena + offA(l - 1), cs_out, nullptr, nullptr);
        float* t = cs_in; cs_in = cs_out; cs_out = t;
    }

    // ---- tail: levels 7..0 + FC (8 blocks x 512 threads, fence-free barrier)
    tail_kernel<<<dim3(NBLK_TAIL), dim3(512), 0, stream>>>(
        arena, Wp, bp, cs_in, cs_out, c_root, W_fc, b_fc, out, ctr);
}